// Round 7
// baseline (148.994 us; speedup 1.0000x reference)
//
#include <hip/hip_runtime.h>

// LSTM(units=64) over T=5, D_IN=1, then Dense(1, relu).  R7.
// fp16 MFMA for h@U (fp32 acc); gates via exp2 + merged rcp:
//   p=(1+ei)(1+eg), q=(1+ef):  c' = (c*p + q*(1-eg)) * rcp(p*q)
//   h = o*tanh(c') = (1-ec) * rcp((1+eo)(1+ec)),  ec = exp2(-2L*c')
// 5 exp2 + 2 rcp per cell; trans issue ~15 cyc/wave64 = ~72% of issue.
// Residency history: pinned at 3 blocks/CU by the unified VGPR+AGPR
// file (R5). R6 tried cap=4 at MB=128 -> spilled (~15MB scratch
// traffic), occupancy unchanged: MB=128 liveness (c=32 regs) > 128.
// R7 = clean test: MB=64 (c=16 regs, hand liveness ~100-110) +
// __launch_bounds__(256,4). Expect no spill + 4th resident block.
// HSTR=68 kept from R6: bank conflicts 2.26M -> 0.16M vs 72.
// Wave w owns gate-cols [w*16,w*16+16) of all 4 gates; Bf pinned via
// volatile asm (R1/R2 remat pathology). h via LDS f16; c in regs in
// C/D layout (col=lane&15, row=quad*4+reg).

typedef _Float16 f16x8 __attribute__((ext_vector_type(8)));
typedef float f32x4 __attribute__((ext_vector_type(4)));

#define MB 64
#define NTHREADS 256
#define HSTR 68

__device__ __forceinline__ float ex2(float x) { return __builtin_amdgcn_exp2f(x); }
__device__ __forceinline__ float rcp(float x) { return __builtin_amdgcn_rcpf(x); }

__global__ __launch_bounds__(NTHREADS, 4) void lstm_fused(
    const float* __restrict__ x,   // [B,5,1]
    const float* __restrict__ W,   // [1,256]  gate order i,f,g,o
    const float* __restrict__ U,   // [64,256]
    const float* __restrict__ b,   // [256]
    const float* __restrict__ Wd,  // [64,1]
    const float* __restrict__ bd,  // [1]
    float* __restrict__ out,       // [B,1]
    int B)
{
    __shared__ _Float16 hbuf[2][64 * HSTR];   // 17.0 KB
    __shared__ float xs[5][MB];               // 1.25 KB, [t][row]
    __shared__ float red[4][64];              // 1 KB
    __shared__ float wds[64];                 // 0.25 KB

    const int tid  = threadIdx.x;
    const int wv   = tid >> 6;
    const int lane = tid & 63;
    const int l15  = lane & 15;
    const int quad = lane >> 4;
    const int row0 = blockIdx.x * MB;

    // stage x transposed to [t][row]; stage Wd
    for (int i = tid; i < MB * 5; i += NTHREADS)
        xs[i % 5][i / 5] = x[row0 * 5 + i];
    if (tid < 64) wds[tid] = Wd[tid];

    const float LOG2E = 1.44269504f;
    const float gscale[4] = {-LOG2E, -LOG2E, -2.0f * LOG2E, -LOG2E};
    const float CSC = -2.0f * LOG2E;

    // U B-fragments loaded ONCE (n = gate*64 + wv*16 + l15,
    // k = kh*32 + quad*8 + j), scaled, cvt f16, pinned vs remat.
    const int ncol = wv * 16 + l15;
    float Wf[4], bf[4];
    f16x8 Bf[4][2];
#pragma unroll
    for (int g = 0; g < 4; ++g) {
        const int n = g * 64 + ncol;
        const float s = gscale[g];
        Wf[g] = W[n] * s;
        bf[g] = b[n] * s;
#pragma unroll
        for (int kh = 0; kh < 2; ++kh) {
            f16x8 v;
#pragma unroll
            for (int j = 0; j < 8; ++j) {
                const int k = kh * 32 + quad * 8 + j;
                v[j] = (_Float16)(U[k * 256 + n] * s);
            }
            Bf[g][kh] = v;
            asm volatile("" : "+v"(Bf[g][kh]));
        }
    }

    float c[4][4];
#pragma unroll
    for (int a = 0; a < 4; ++a)
#pragma unroll
        for (int r = 0; r < 4; ++r) c[a][r] = 0.0f;

    __syncthreads();  // xs visible

    // ---- t = 0 (h=0, c=0): c = i*g, h = o*tanh(c) ----
#pragma unroll
    for (int rt = 0; rt < 4; ++rt) {
        const f32x4 xv = *(const f32x4*)&xs[0][rt * 16 + quad * 4];
#pragma unroll
        for (int r = 0; r < 4; ++r) {
            const int rloc = rt * 16 + quad * 4 + r;
            const float ei = ex2(__builtin_fmaf(xv[r], Wf[0], bf[0]));
            const float eg = ex2(__builtin_fmaf(xv[r], Wf[2], bf[2]));
            const float eo = ex2(__builtin_fmaf(xv[r], Wf[3], bf[3]));
            const float r1 = rcp((1.0f + ei) * (1.0f + eg));
            const float cn = (1.0f - eg) * r1;            // i*g
            c[rt][r] = cn;
            const float ec = ex2(cn * CSC);
            const float r2 = rcp((1.0f + eo) * (1.0f + ec));
            hbuf[0][rloc * HSTR + ncol] = (_Float16)((1.0f - ec) * r2);
        }
    }

    // ---- t = 1..4 ----
#pragma unroll
    for (int t = 1; t < 5; ++t) {
        const int src = (t + 1) & 1;
        const int dst = t & 1;
        __syncthreads();
#pragma unroll
        for (int rt = 0; rt < 4; ++rt) {
            const int arow = rt * 16 + l15;   // A layout: m = lane&15
            const f16x8 a0 = *(const f16x8*)&hbuf[src][arow * HSTR + quad * 8];
            const f16x8 a1 = *(const f16x8*)&hbuf[src][arow * HSTR + 32 + quad * 8];
            const f32x4 xv = *(const f32x4*)&xs[t][rt * 16 + quad * 4];
            f32x4 acc[4];
#pragma unroll
            for (int g = 0; g < 4; ++g) {
                f32x4 z;
#pragma unroll
                for (int r = 0; r < 4; ++r)
                    z[r] = __builtin_fmaf(xv[r], Wf[g], bf[g]);
                z = __builtin_amdgcn_mfma_f32_16x16x32_f16(a0, Bf[g][0], z, 0, 0, 0);
                z = __builtin_amdgcn_mfma_f32_16x16x32_f16(a1, Bf[g][1], z, 0, 0, 0);
                acc[g] = z;
            }
#pragma unroll
            for (int r = 0; r < 4; ++r) {
                const int rloc = rt * 16 + quad * 4 + r;
                const float ei = ex2(acc[0][r]);
                const float ef = ex2(acc[1][r]);
                const float eg = ex2(acc[2][r]);
                const float eo = ex2(acc[3][r]);
                const float p  = (1.0f + ei) * (1.0f + eg);
                const float q  = 1.0f + ef;
                const float num = __builtin_fmaf(c[rt][r], p, q * (1.0f - eg));
                const float cn  = num * rcp(p * q);
                c[rt][r] = cn;
                const float ec = ex2(cn * CSC);
                const float r2 = rcp((1.0f + eo) * (1.0f + ec));
                hbuf[dst][rloc * HSTR + ncol] = (_Float16)((1.0f - ec) * r2);
            }
        }
    }

    __syncthreads();  // h(t=4) complete in hbuf[0]

    // Dense(1, relu)
    {
        const int row = tid & 63;
        const int q   = tid >> 6;
        float s = 0.0f;
#pragma unroll
        for (int j = 0; j < 16; ++j)
            s += (float)hbuf[0][row * HSTR + q * 16 + j] * wds[q * 16 + j];
        red[q][row] = s;
    }
    __syncthreads();
    if (tid < 64) {
        const float r = red[0][tid] + red[1][tid] + red[2][tid] + red[3][tid] + bd[0];
        out[row0 + tid] = fmaxf(r, 0.0f);
    }
}

extern "C" void kernel_launch(void* const* d_in, const int* in_sizes, int n_in,
                              void* d_out, int out_size, void* d_ws, size_t ws_size,
                              hipStream_t stream) {
    const float* x  = (const float*)d_in[0];
    const float* W  = (const float*)d_in[1];
    const float* U  = (const float*)d_in[2];
    const float* b  = (const float*)d_in[3];
    const float* Wd = (const float*)d_in[4];
    const float* bd = (const float*)d_in[5];
    float* out = (float*)d_out;
    const int B = in_sizes[0] / 5;
    const int grid = B / MB;   // 4096 blocks
    lstm_fused<<<grid, NTHREADS, 0, stream>>>(x, W, U, b, Wd, bd, out, B);
}

// Round 8
// 141.647 us; speedup vs baseline: 1.0519x; 1.0519x over previous
//
#include <hip/hip_runtime.h>

// LSTM(units=64) over T=5, D_IN=1, then Dense(1, relu).  R8.
// fp16 MFMA for h@U (fp32 acc); gates via exp2 + merged rcp:
//   p=(1+ei)(1+eg), q=(1+ef):  c' = (c*p + q*(1-eg)) * rcp(p*q)
//   h = o*tanh(c') = (1-ec) * rcp((1+eo)(1+ec)),  ec = exp2(-2L*c')
// Issue model (stable across R4-R7): per cell 7 trans x ~15.5cyc = 108
// + ~35 regular; busy ~81us-equiv at ~80% wall util. Occupancy is
// PINNED at ~3 blocks/CU regardless of LDS/reg-caps/block size
// (R5/R6/R7) -- utilization lever exhausted.
// R8: the only reducible term is the ~35 regular cyc/cell. gfx950 has
// VOP3P packed dual-fp32 (v_pk_fma_f32 etc). Gate math rewritten over
// cell-PAIRS as float2 ext-vectors (trans remain scalar per element);
// if the backend packs, regular issue halves (~13% total). Arithmetic
// order is identical to R7 -> absmax must stay exactly 1.953e-3.
// Wave w owns gate-cols [w*16,w*16+16) of all 4 gates; Bf pinned via
// volatile asm (R1/R2 remat pathology). h via LDS f16 (HSTR=68: bank
// conflicts 0.16M vs 2.26M at 72). c in regs in C/D layout
// (col=lane&15, row=quad*4+reg).

typedef _Float16 f16x8 __attribute__((ext_vector_type(8)));
typedef float f32x4 __attribute__((ext_vector_type(4)));
typedef float f32x2 __attribute__((ext_vector_type(2)));

#define MB 64
#define NTHREADS 256
#define HSTR 68

__device__ __forceinline__ float ex2(float x) { return __builtin_amdgcn_exp2f(x); }
__device__ __forceinline__ float rcp(float x) { return __builtin_amdgcn_rcpf(x); }
__device__ __forceinline__ f32x2 fma2(f32x2 a, f32x2 b, f32x2 c) {
    return __builtin_elementwise_fma(a, b, c);
}

__global__ __launch_bounds__(NTHREADS, 3) void lstm_fused(
    const float* __restrict__ x,   // [B,5,1]
    const float* __restrict__ W,   // [1,256]  gate order i,f,g,o
    const float* __restrict__ U,   // [64,256]
    const float* __restrict__ b,   // [256]
    const float* __restrict__ Wd,  // [64,1]
    const float* __restrict__ bd,  // [1]
    float* __restrict__ out,       // [B,1]
    int B)
{
    __shared__ _Float16 hbuf[2][64 * HSTR];   // 17.0 KB
    __shared__ float xs[5][MB];               // 1.25 KB, [t][row]
    __shared__ float red[4][64];              // 1 KB
    __shared__ float wds[64];                 // 0.25 KB

    const int tid  = threadIdx.x;
    const int wv   = tid >> 6;
    const int lane = tid & 63;
    const int l15  = lane & 15;
    const int quad = lane >> 4;
    const int row0 = blockIdx.x * MB;

    // stage x transposed to [t][row]; stage Wd
    for (int i = tid; i < MB * 5; i += NTHREADS)
        xs[i % 5][i / 5] = x[row0 * 5 + i];
    if (tid < 64) wds[tid] = Wd[tid];

    const float LOG2E = 1.44269504f;
    const float gscale[4] = {-LOG2E, -LOG2E, -2.0f * LOG2E, -LOG2E};
    const float CSC = -2.0f * LOG2E;

    // U B-fragments loaded ONCE (n = gate*64 + wv*16 + l15,
    // k = kh*32 + quad*8 + j), scaled, cvt f16, pinned vs remat.
    const int ncol = wv * 16 + l15;
    float Wf[4], bf[4];
    f16x8 Bf[4][2];
#pragma unroll
    for (int g = 0; g < 4; ++g) {
        const int n = g * 64 + ncol;
        const float s = gscale[g];
        Wf[g] = W[n] * s;
        bf[g] = b[n] * s;
#pragma unroll
        for (int kh = 0; kh < 2; ++kh) {
            f16x8 v;
#pragma unroll
            for (int j = 0; j < 8; ++j) {
                const int k = kh * 32 + quad * 8 + j;
                v[j] = (_Float16)(U[k * 256 + n] * s);
            }
            Bf[g][kh] = v;
            asm volatile("" : "+v"(Bf[g][kh]));
        }
    }

    // cell state as float2 pairs: c[rt][pr] covers rows quad*4+2pr+{0,1}
    f32x2 cst[4][2];
#pragma unroll
    for (int a = 0; a < 4; ++a)
#pragma unroll
        for (int pr = 0; pr < 2; ++pr) cst[a][pr] = (f32x2){0.f, 0.f};

    __syncthreads();  // xs visible

    // ---- t = 0 (h=0, c=0): c = i*g, h = o*tanh(c) ----
#pragma unroll
    for (int rt = 0; rt < 4; ++rt) {
        const f32x4 xv = *(const f32x4*)&xs[0][rt * 16 + quad * 4];
#pragma unroll
        for (int pr = 0; pr < 2; ++pr) {
            const f32x2 xp = {xv[2 * pr], xv[2 * pr + 1]};
            const f32x2 zi = fma2(xp, (f32x2){Wf[0], Wf[0]}, (f32x2){bf[0], bf[0]});
            const f32x2 zg = fma2(xp, (f32x2){Wf[2], Wf[2]}, (f32x2){bf[2], bf[2]});
            const f32x2 zo = fma2(xp, (f32x2){Wf[3], Wf[3]}, (f32x2){bf[3], bf[3]});
            const f32x2 ei = {ex2(zi.x), ex2(zi.y)};
            const f32x2 eg = {ex2(zg.x), ex2(zg.y)};
            const f32x2 eo = {ex2(zo.x), ex2(zo.y)};
            const f32x2 pq = (1.0f + ei) * (1.0f + eg);
            const f32x2 r1 = {rcp(pq.x), rcp(pq.y)};
            const f32x2 cn = (1.0f - eg) * r1;            // i*g
            cst[rt][pr] = cn;
            const f32x2 sc = cn * CSC;
            const f32x2 ec = {ex2(sc.x), ex2(sc.y)};
            const f32x2 dn = (1.0f + eo) * (1.0f + ec);
            const f32x2 r2 = {rcp(dn.x), rcp(dn.y)};
            const f32x2 h2 = (1.0f - ec) * r2;
            const int rb = rt * 16 + quad * 4 + 2 * pr;
            hbuf[0][rb * HSTR + ncol]       = (_Float16)h2.x;
            hbuf[0][(rb + 1) * HSTR + ncol] = (_Float16)h2.y;
        }
    }

    // ---- t = 1..4 ----
#pragma unroll
    for (int t = 1; t < 5; ++t) {
        const int src = (t + 1) & 1;
        const int dst = t & 1;
        __syncthreads();
#pragma unroll
        for (int rt = 0; rt < 4; ++rt) {
            const int arow = rt * 16 + l15;   // A layout: m = lane&15
            const f16x8 a0 = *(const f16x8*)&hbuf[src][arow * HSTR + quad * 8];
            const f16x8 a1 = *(const f16x8*)&hbuf[src][arow * HSTR + 32 + quad * 8];
            const f32x4 xv = *(const f32x4*)&xs[t][rt * 16 + quad * 4];
            const f32x2 xlo = {xv[0], xv[1]};
            const f32x2 xhi = {xv[2], xv[3]};
            f32x4 acc[4];
#pragma unroll
            for (int g = 0; g < 4; ++g) {
                const f32x2 wg = {Wf[g], Wf[g]};
                const f32x2 bg = {bf[g], bf[g]};
                const f32x2 zlo = fma2(xlo, wg, bg);
                const f32x2 zhi = fma2(xhi, wg, bg);
                f32x4 z = {zlo.x, zlo.y, zhi.x, zhi.y};
                z = __builtin_amdgcn_mfma_f32_16x16x32_f16(a0, Bf[g][0], z, 0, 0, 0);
                z = __builtin_amdgcn_mfma_f32_16x16x32_f16(a1, Bf[g][1], z, 0, 0, 0);
                acc[g] = z;
            }
#pragma unroll
            for (int pr = 0; pr < 2; ++pr) {
                const f32x2 ei = {ex2(acc[0][2 * pr]), ex2(acc[0][2 * pr + 1])};
                const f32x2 ef = {ex2(acc[1][2 * pr]), ex2(acc[1][2 * pr + 1])};
                const f32x2 eg = {ex2(acc[2][2 * pr]), ex2(acc[2][2 * pr + 1])};
                const f32x2 eo = {ex2(acc[3][2 * pr]), ex2(acc[3][2 * pr + 1])};
                const f32x2 p  = (1.0f + ei) * (1.0f + eg);
                const f32x2 q  = 1.0f + ef;
                const f32x2 num = fma2(cst[rt][pr], p, q * (1.0f - eg));
                const f32x2 pq  = p * q;
                const f32x2 ipq = {rcp(pq.x), rcp(pq.y)};
                const f32x2 cn  = num * ipq;
                cst[rt][pr] = cn;
                const f32x2 sc = cn * CSC;
                const f32x2 ec = {ex2(sc.x), ex2(sc.y)};
                const f32x2 dn = (1.0f + eo) * (1.0f + ec);
                const f32x2 r2 = {rcp(dn.x), rcp(dn.y)};
                const f32x2 h2 = (1.0f - ec) * r2;
                const int rb = rt * 16 + quad * 4 + 2 * pr;
                hbuf[dst][rb * HSTR + ncol]       = (_Float16)h2.x;
                hbuf[dst][(rb + 1) * HSTR + ncol] = (_Float16)h2.y;
            }
        }
    }

    __syncthreads();  // h(t=4) complete in hbuf[0]

    // Dense(1, relu)
    {
        const int row = tid & 63;
        const int q   = tid >> 6;
        float s = 0.0f;
#pragma unroll
        for (int j = 0; j < 16; ++j)
            s += (float)hbuf[0][row * HSTR + q * 16 + j] * wds[q * 16 + j];
        red[q][row] = s;
    }
    __syncthreads();
    if (tid < 64) {
        const float r = red[0][tid] + red[1][tid] + red[2][tid] + red[3][tid] + bd[0];
        out[row0 + tid] = fmaxf(r, 0.0f);
    }
}

extern "C" void kernel_launch(void* const* d_in, const int* in_sizes, int n_in,
                              void* d_out, int out_size, void* d_ws, size_t ws_size,
                              hipStream_t stream) {
    const float* x  = (const float*)d_in[0];
    const float* W  = (const float*)d_in[1];
    const float* U  = (const float*)d_in[2];
    const float* b  = (const float*)d_in[3];
    const float* Wd = (const float*)d_in[4];
    const float* bd = (const float*)d_in[5];
    float* out = (float*)d_out;
    const int B = in_sizes[0] / 5;
    const int grid = B / MB;   // 4096 blocks
    lstm_fused<<<grid, NTHREADS, 0, stream>>>(x, W, U, b, Wd, bd, out, B);
}

// Round 9
// 139.787 us; speedup vs baseline: 1.0659x; 1.0133x over previous
//
#include <hip/hip_runtime.h>

// LSTM(units=64) over T=5, D_IN=1, then Dense(1, relu).  R9.
// fp16 MFMA for h@U (fp32 acc); gates via exp2 + merged rcp over
// float2 cell-pairs (v_pk_* packed fp32, R8: -4.4%):
//   p=(1+ei)(1+eg), q=(1+ef):  c' = (c*p + q*(1-eg)) * rcp(p*q)
//   h = o*tanh(c') = (1-ec) * rcp((1+eo)(1+ec)),  ec = exp2(-2L*c')
// Ledger (R8): busy 67us = trans 57.6 (7x~15.5cyc x 80 cells x 16
// waves/SIMD) + regular ~10; wall 95.8 -> 29us idle = dep-stall +
// barrier convergence at 3 resident waves/SIMD (pin unbreakable:
// R5/R6/R7). R9 = R5's fat-block lever (the one utilization lever
// that measured +4%) on top of R8: MB=128, 8 independent rt-tiles
// per barrier interval, preamble amortized 2x. cap=3 (R6's spill was
// cap=4+MB=128; R5 ran MB=128 fine).
// Wave w owns gate-cols [w*16,w*16+16) of all 4 gates; Bf pinned via
// volatile asm (R1/R2 remat). h via LDS f16 HSTR=68 (conflicts 14x
// down vs 72). c in regs, C/D layout (col=lane&15, row=quad*4+reg).

typedef _Float16 f16x8 __attribute__((ext_vector_type(8)));
typedef float f32x4 __attribute__((ext_vector_type(4)));
typedef float f32x2 __attribute__((ext_vector_type(2)));

#define MB 128       // rows per block (2 groups of 64)
#define NTHREADS 256
#define HSTR 68

__device__ __forceinline__ float ex2(float x) { return __builtin_amdgcn_exp2f(x); }
__device__ __forceinline__ float rcp(float x) { return __builtin_amdgcn_rcpf(x); }
__device__ __forceinline__ f32x2 fma2(f32x2 a, f32x2 b, f32x2 c) {
    return __builtin_elementwise_fma(a, b, c);
}

__global__ __launch_bounds__(NTHREADS, 3) void lstm_fused(
    const float* __restrict__ x,   // [B,5,1]
    const float* __restrict__ W,   // [1,256]  gate order i,f,g,o
    const float* __restrict__ U,   // [64,256]
    const float* __restrict__ b,   // [256]
    const float* __restrict__ Wd,  // [64,1]
    const float* __restrict__ bd,  // [1]
    float* __restrict__ out,       // [B,1]
    int B)
{
    __shared__ _Float16 hbuf[2][2][64 * HSTR];  // [group][parity] 34.0 KB
    __shared__ float xs[5][MB];                 // 2.5 KB, [t][row]
    __shared__ float red[2][MB];                // 1 KB
    __shared__ float wds[64];                   // 0.25 KB

    const int tid  = threadIdx.x;
    const int wv   = tid >> 6;
    const int lane = tid & 63;
    const int l15  = lane & 15;
    const int quad = lane >> 4;
    const int row0 = blockIdx.x * MB;

    // stage x transposed to [t][row]; stage Wd
    for (int i = tid; i < MB * 5; i += NTHREADS)
        xs[i % 5][i / 5] = x[row0 * 5 + i];
    if (tid < 64) wds[tid] = Wd[tid];

    const float LOG2E = 1.44269504f;
    const float gscale[4] = {-LOG2E, -LOG2E, -2.0f * LOG2E, -LOG2E};
    const float CSC = -2.0f * LOG2E;

    // U B-fragments loaded ONCE (n = gate*64 + wv*16 + l15,
    // k = kh*32 + quad*8 + j), scaled, cvt f16, pinned vs remat.
    const int ncol = wv * 16 + l15;
    float Wf[4], bf[4];
    f16x8 Bf[4][2];
#pragma unroll
    for (int g = 0; g < 4; ++g) {
        const int n = g * 64 + ncol;
        const float s = gscale[g];
        Wf[g] = W[n] * s;
        bf[g] = b[n] * s;
#pragma unroll
        for (int kh = 0; kh < 2; ++kh) {
            f16x8 v;
#pragma unroll
            for (int j = 0; j < 8; ++j) {
                const int k = kh * 32 + quad * 8 + j;
                v[j] = (_Float16)(U[k * 256 + n] * s);
            }
            Bf[g][kh] = v;
            asm volatile("" : "+v"(Bf[g][kh]));
        }
    }

    // cell state: [group][rt][pair], pair pr covers rows quad*4+2pr+{0,1}
    f32x2 cst[2][4][2];
#pragma unroll
    for (int gr = 0; gr < 2; ++gr)
#pragma unroll
        for (int a = 0; a < 4; ++a)
#pragma unroll
            for (int pr = 0; pr < 2; ++pr) cst[gr][a][pr] = (f32x2){0.f, 0.f};

    __syncthreads();  // xs visible

    // ---- t = 0 (h=0, c=0): c = i*g, h = o*tanh(c) ----
#pragma unroll
    for (int gr = 0; gr < 2; ++gr) {
#pragma unroll
        for (int rt = 0; rt < 4; ++rt) {
            const f32x4 xv = *(const f32x4*)&xs[0][gr * 64 + rt * 16 + quad * 4];
#pragma unroll
            for (int pr = 0; pr < 2; ++pr) {
                const f32x2 xp = {xv[2 * pr], xv[2 * pr + 1]};
                const f32x2 zi = fma2(xp, (f32x2){Wf[0], Wf[0]}, (f32x2){bf[0], bf[0]});
                const f32x2 zg = fma2(xp, (f32x2){Wf[2], Wf[2]}, (f32x2){bf[2], bf[2]});
                const f32x2 zo = fma2(xp, (f32x2){Wf[3], Wf[3]}, (f32x2){bf[3], bf[3]});
                const f32x2 ei = {ex2(zi.x), ex2(zi.y)};
                const f32x2 eg = {ex2(zg.x), ex2(zg.y)};
                const f32x2 eo = {ex2(zo.x), ex2(zo.y)};
                const f32x2 pq = (1.0f + ei) * (1.0f + eg);
                const f32x2 r1 = {rcp(pq.x), rcp(pq.y)};
                const f32x2 cn = (1.0f - eg) * r1;            // i*g
                cst[gr][rt][pr] = cn;
                const f32x2 sc = cn * CSC;
                const f32x2 ec = {ex2(sc.x), ex2(sc.y)};
                const f32x2 dn = (1.0f + eo) * (1.0f + ec);
                const f32x2 r2 = {rcp(dn.x), rcp(dn.y)};
                const f32x2 h2 = (1.0f - ec) * r2;
                const int rb = rt * 16 + quad * 4 + 2 * pr;
                hbuf[gr][0][rb * HSTR + ncol]       = (_Float16)h2.x;
                hbuf[gr][0][(rb + 1) * HSTR + ncol] = (_Float16)h2.y;
            }
        }
    }

    // ---- t = 1..4 ----
#pragma unroll
    for (int t = 1; t < 5; ++t) {
        const int src = (t + 1) & 1;
        const int dst = t & 1;
        __syncthreads();
#pragma unroll
        for (int gr = 0; gr < 2; ++gr) {
#pragma unroll
            for (int rt = 0; rt < 4; ++rt) {
                const int arow = rt * 16 + l15;   // A layout: m = lane&15
                const f16x8 a0 = *(const f16x8*)&hbuf[gr][src][arow * HSTR + quad * 8];
                const f16x8 a1 = *(const f16x8*)&hbuf[gr][src][arow * HSTR + 32 + quad * 8];
                const f32x4 xv = *(const f32x4*)&xs[t][gr * 64 + rt * 16 + quad * 4];
                const f32x2 xlo = {xv[0], xv[1]};
                const f32x2 xhi = {xv[2], xv[3]};
                f32x4 acc[4];
#pragma unroll
                for (int g = 0; g < 4; ++g) {
                    const f32x2 wg = {Wf[g], Wf[g]};
                    const f32x2 bg = {bf[g], bf[g]};
                    const f32x2 zlo = fma2(xlo, wg, bg);
                    const f32x2 zhi = fma2(xhi, wg, bg);
                    f32x4 z = {zlo.x, zlo.y, zhi.x, zhi.y};
                    z = __builtin_amdgcn_mfma_f32_16x16x32_f16(a0, Bf[g][0], z, 0, 0, 0);
                    z = __builtin_amdgcn_mfma_f32_16x16x32_f16(a1, Bf[g][1], z, 0, 0, 0);
                    acc[g] = z;
                }
#pragma unroll
                for (int pr = 0; pr < 2; ++pr) {
                    const f32x2 ei = {ex2(acc[0][2 * pr]), ex2(acc[0][2 * pr + 1])};
                    const f32x2 ef = {ex2(acc[1][2 * pr]), ex2(acc[1][2 * pr + 1])};
                    const f32x2 eg = {ex2(acc[2][2 * pr]), ex2(acc[2][2 * pr + 1])};
                    const f32x2 eo = {ex2(acc[3][2 * pr]), ex2(acc[3][2 * pr + 1])};
                    const f32x2 p  = (1.0f + ei) * (1.0f + eg);
                    const f32x2 q  = 1.0f + ef;
                    const f32x2 num = fma2(cst[gr][rt][pr], p, q * (1.0f - eg));
                    const f32x2 pq  = p * q;
                    const f32x2 ipq = {rcp(pq.x), rcp(pq.y)};
                    const f32x2 cn  = num * ipq;
                    cst[gr][rt][pr] = cn;
                    const f32x2 sc = cn * CSC;
                    const f32x2 ec = {ex2(sc.x), ex2(sc.y)};
                    const f32x2 dn = (1.0f + eo) * (1.0f + ec);
                    const f32x2 r2 = {rcp(dn.x), rcp(dn.y)};
                    const f32x2 h2 = (1.0f - ec) * r2;
                    const int rb = rt * 16 + quad * 4 + 2 * pr;
                    hbuf[gr][dst][rb * HSTR + ncol]       = (_Float16)h2.x;
                    hbuf[gr][dst][(rb + 1) * HSTR + ncol] = (_Float16)h2.y;
                }
            }
        }
    }

    __syncthreads();  // h(t=4) complete in hbuf[*][0]

    // Dense(1, relu): each thread sums 32 of the 64 units for one row.
    {
        const int row = tid & 127;          // 0..127
        const int qh  = tid >> 7;           // 0..1
        const int gr  = row >> 6;
        const int rl  = row & 63;
        float s = 0.0f;
#pragma unroll
        for (int j = 0; j < 32; ++j)
            s += (float)hbuf[gr][0][rl * HSTR + qh * 32 + j] * wds[qh * 32 + j];
        red[qh][row] = s;
    }
    __syncthreads();
    if (tid < MB) {
        const float r = red[0][tid] + red[1][tid] + bd[0];
        out[row0 + tid] = fmaxf(r, 0.0f);
    }
}

extern "C" void kernel_launch(void* const* d_in, const int* in_sizes, int n_in,
                              void* d_out, int out_size, void* d_ws, size_t ws_size,
                              hipStream_t stream) {
    const float* x  = (const float*)d_in[0];
    const float* W  = (const float*)d_in[1];
    const float* U  = (const float*)d_in[2];
    const float* b  = (const float*)d_in[3];
    const float* Wd = (const float*)d_in[4];
    const float* bd = (const float*)d_in[5];
    float* out = (float*)d_out;
    const int B = in_sizes[0] / 5;
    const int grid = B / MB;   // 2048 blocks
    lstm_fused<<<grid, NTHREADS, 0, stream>>>(x, W, U, b, Wd, bd, out, B);
}